// Round 5
// baseline (6508.665 us; speedup 1.0000x reference)
//
#include <hip/hip_runtime.h>

typedef _Float16 half_t;
typedef _Float16 f16x2 __attribute__((ext_vector_type(2)));
typedef _Float16 f16x8 __attribute__((ext_vector_type(8)));
typedef float f32x4 __attribute__((ext_vector_type(4)));

#define B_SZ 64
#define T_SZ 2048
#define F_SZ 256
#define H_SZ 512
#define O_SZ 128
#define NCH 32      // chunks
#define CH 64       // timesteps per chunk

#if defined(__has_builtin)
#if __has_builtin(__builtin_amdgcn_fdot2)
#define HAS_FDOT2 1
#endif
#if __has_builtin(__builtin_amdgcn_rcpf)
#define HAS_RCPF 1
#endif
#endif
#ifndef HAS_FDOT2
#define HAS_FDOT2 0
#endif
#ifndef HAS_RCPF
#define HAS_RCPF 0
#endif

static __device__ __forceinline__ float fdot2(unsigned int w, unsigned int h, float acc) {
#if HAS_FDOT2
    return __builtin_amdgcn_fdot2(__builtin_bit_cast(f16x2, w), __builtin_bit_cast(f16x2, h), acc, false);
#else
    f16x2 wv = __builtin_bit_cast(f16x2, w);
    f16x2 hv = __builtin_bit_cast(f16x2, h);
    return acc + (float)wv[0] * (float)hv[0] + (float)wv[1] * (float)hv[1];
#endif
}

static __device__ __forceinline__ unsigned int pack_pair(float a, float b) {
    f16x2 p;
    p[0] = (half_t)a;
    p[1] = (half_t)b;
    return __builtin_bit_cast(unsigned int, p);
}

static __device__ __forceinline__ float fast_rcp(float x) {
#if HAS_RCPF
    return __builtin_amdgcn_rcpf(x);
#else
    return 1.0f / x;
#endif
}

// DPP-based in-wave add: x + x[lane ^ pattern], VALU pipe only (no LDS).
// 0x0B1 = quad_perm [1,0,3,2]  (xor 1)
// 0x04E = quad_perm [2,3,0,1]  (xor 2)
// 0x141 = row_half_mirror      (xor 7 within each 8-lane half-row)
template<int CTRL>
static __device__ __forceinline__ float dpp_add(float x) {
    int y = __builtin_amdgcn_mov_dpp(__builtin_bit_cast(int, x), CTRL, 0xF, 0xF, true);
    return x + __builtin_bit_cast(float, y);
}

// Per-step barrier: LDS-only drain. __syncthreads() would add a vmcnt(0)
// drain of the in-flight xp prefetch / res store every step.
static __device__ __forceinline__ void step_barrier() {
    __builtin_amdgcn_sched_barrier(0);
    asm volatile("s_waitcnt lgkmcnt(0)" ::: "memory");
    __builtin_amdgcn_s_barrier();
    __builtin_amdgcn_sched_barrier(0);
}

// ---------------- prep ----------------

__global__ void cvt_f32_f16(const float* __restrict__ src, half_t* __restrict__ dst, int n) {
    int i = blockIdx.x * 256 + threadIdx.x;
    if (i < n) dst[i] = (half_t)src[i];
}

__global__ void zero_flags(unsigned int* __restrict__ p, int n) {
    int i = blockIdx.x * 256 + threadIdx.x;
    if (i < n) p[i] = 0u;
}

// Pack W_hh overflow pairs 30,31 into a per-thread coalesced global layout:
// WovG[(layer*4 + j)*512 + tid], j = (c-30)*2 + rowhalf. 64 KB total ->
// L1/L2-resident; read by the rec loop every step on the (idle) VMEM pipe.
__global__ __launch_bounds__(256) void pack_wov(const float* __restrict__ Whh0,
                                                const float* __restrict__ Whh1,
                                                uint4* __restrict__ WovG)
{
    int i = blockIdx.x * 256 + threadIdx.x;   // 0..1023
    if (i >= 1024) return;
    const int layer = i >> 9;
    const int tid   = i & 511;
    const float* Whh = layer ? Whh1 : Whh0;
    const int l = tid & 63, s = tid >> 6;
    const int q = l >> 3, sp = l & 7;
    for (int c2 = 0; c2 < 2; c2++) {
        const int c = 30 + c2;
        for (int rh = 0; rh < 2; rh++) {
            unsigned int qv[4];
            for (int j = 0; j < 4; j++) {
                const int r = rh * 4 + j;
                const float* wrow = Whh + (size_t)(64 * s + 8 * q + r) * H_SZ + 64 * sp;
                qv[j] = pack_pair(wrow[2 * c], wrow[2 * c + 1]);
            }
            uint4 v;
            v.x = qv[0]; v.y = qv[1]; v.z = qv[2]; v.w = qv[3];
            WovG[((size_t)layer * 4 + (c2 * 2 + rh)) * 512 + tid] = v;
        }
    }
}

// ---------------- xp0 GEMM (MFMA f16), layer-0 input projection ----------------
template<bool A_F32, int K>
__global__ __launch_bounds__(256) void gemm_xp(const void* __restrict__ Aptr,
                                               const half_t* __restrict__ Bw,
                                               const float* __restrict__ bias1,
                                               const float* __restrict__ bias2,
                                               half_t* __restrict__ Cout)
{
    const int nt   = blockIdx.x & 7;
    const int mt   = blockIdx.x >> 3;
    const int wave = threadIdx.x >> 6;
    const int lane = threadIdx.x & 63;
    const int mrow = mt * 64 + wave * 16 + (lane & 15);
    const int koff = (lane >> 4) * 8;

    f32x4 acc[4];
#pragma unroll
    for (int i = 0; i < 4; i++) acc[i] = (f32x4){0.f, 0.f, 0.f, 0.f};

#pragma unroll 2
    for (int k0 = 0; k0 < K; k0 += 32) {
        f16x8 a;
        if (A_F32) {
            const float* ap = (const float*)Aptr + (size_t)mrow * K + (k0 + koff);
            float4 v0 = ((const float4*)ap)[0];
            float4 v1 = ((const float4*)ap)[1];
            a[0] = (half_t)v0.x; a[1] = (half_t)v0.y; a[2] = (half_t)v0.z; a[3] = (half_t)v0.w;
            a[4] = (half_t)v1.x; a[5] = (half_t)v1.y; a[6] = (half_t)v1.z; a[7] = (half_t)v1.w;
        } else {
            const half_t* ap = (const half_t*)Aptr + (size_t)mrow * K + (k0 + koff);
            a = *(const f16x8*)ap;
        }
#pragma unroll
        for (int cb = 0; cb < 4; cb++) {
            const int col = nt * 64 + cb * 16 + (lane & 15);
            f16x8 bfrag = *(const f16x8*)(Bw + (size_t)col * K + (k0 + koff));
            acc[cb] = __builtin_amdgcn_mfma_f32_16x16x32_f16(a, bfrag, acc[cb], 0, 0, 0);
        }
    }
    const int rbase = mt * 64 + wave * 16 + (lane >> 4) * 4;
#pragma unroll
    for (int cb = 0; cb < 4; cb++) {
        const int col = nt * 64 + cb * 16 + (lane & 15);
        const float bsum = bias1[col] + bias2[col];
#pragma unroll
        for (int r = 0; r < 4; r++) {
            Cout[(size_t)(rbase + r) * H_SZ + col] = (half_t)(acc[cb][r] + bsum);
        }
    }
}

// ---------------- mega-kernel: pipelined 2-layer RNN ----------------
// 192 blocks x 512 threads, role = blockIdx.x % 3, b = blockIdx.x / 3:
//  role 0: layer-0 recurrence on bufA (xp0 -> res in place); releases
//          flags0[b][chunk] after each 64-step chunk (agent scope).
//  role 1: xp1 producer: polls flags0, MFMA-GEMMs res chunk @ W_ih1^T + bias
//          into bufB, releases flags1[b][chunk].
//  role 2: layer-1 recurrence on bufB; polls flags1; writes hT at t=T-1.
//
// Rec decomposition (intra-wave K-split): wave s owns output rows 64s..64s+63.
// Lane l = 8q + sp computes rows 64s+8q+{0..7} over K-columns 64sp..64sp+63.
// W split across three pipes to balance them (regfile is 100% full at
// 2 waves/SIMD -> 6 pairs must overflow; LDS pipe was the binding pipe at
// ~1150cy/step for a 12-read overflow, VMEM was idle):
//   pairs  0..25 -> registers (208 u32, VGPR+AGPR)
//   pairs 26..29 -> LDS (8 x ds_read_b128 / thread / step)
//   pairs 30..31 -> global WovG (4 x dwordx4 / thread / step, L1-resident;
//                   WovG param is NOT __restrict__ so may-alias with the res
//                   stores forces a per-step reload instead of reg-hoisting)
// Row sums reduced across the 8 sp-lanes with 3 DPP adds; lane keeps acc[sp]
// via cndmask tree -> element e = tid. h exchanged cross-wave through a
// parity-double-buffered, pad-swizzled LDS f16 buffer. One lgkm-only barrier
// per step.
__global__ __launch_bounds__(512, 2)
void rnn_mega(half_t* bufA, half_t* bufB,
              const float* __restrict__ Whh0, const float* __restrict__ Whh1,
              const half_t* __restrict__ Wih1h,
              const float* __restrict__ h0_0, const float* __restrict__ h0_1,
              const float* __restrict__ b_ih1, const float* __restrict__ b_hh1,
              const uint4* WovG,
              float* hT,
              unsigned int* flags0, unsigned int* flags1)
{
    __shared__ __align__(16) uint4 wlds[8 * 512];       // 32 KB (W overflow pairs 26..29)
    __shared__ __align__(16) half_t hpad[2][8 * 72];    // 2.25 KB (h, padded slices)

    const int role = blockIdx.x % 3;
    const int b    = blockIdx.x / 3;
    const int tid  = threadIdx.x;
    const int l    = tid & 63;
    const int s    = tid >> 6;

    if (role == 1) {
        // ---------- xp1 chunk-GEMM producer ----------
        const int w = s, lane = l;
        const int koff = (lane >> 4) * 8;
        for (int chunk = 0; chunk < NCH; chunk++) {
            if (tid == 0) {
                while (__hip_atomic_load(&flags0[b * NCH + chunk], __ATOMIC_ACQUIRE,
                                         __HIP_MEMORY_SCOPE_AGENT) == 0u)
                    __builtin_amdgcn_s_sleep(2);
            }
            __syncthreads();   // all threads gated; acquire-inv done by wave 0
            const int t0 = chunk * CH;

            f32x4 gac[4][4];
#pragma unroll
            for (int rt = 0; rt < 4; rt++)
#pragma unroll
                for (int cb = 0; cb < 4; cb++) gac[rt][cb] = (f32x4){0.f, 0.f, 0.f, 0.f};

#pragma unroll 1
            for (int k0 = 0; k0 < H_SZ; k0 += 32) {
                f16x8 bf[4];
#pragma unroll
                for (int cb = 0; cb < 4; cb++)
                    bf[cb] = *(const f16x8*)(Wih1h +
                              (size_t)(64 * w + 16 * cb + (lane & 15)) * H_SZ + k0 + koff);
#pragma unroll
                for (int rt = 0; rt < 4; rt++) {
                    const f16x8 a = *(const f16x8*)((const half_t*)bufA +
                              ((size_t)b * T_SZ + t0 + rt * 16 + (lane & 15)) * H_SZ + k0 + koff);
#pragma unroll
                    for (int cb = 0; cb < 4; cb++)
                        gac[rt][cb] = __builtin_amdgcn_mfma_f32_16x16x32_f16(a, bf[cb], gac[rt][cb], 0, 0, 0);
                }
            }
#pragma unroll
            for (int rt = 0; rt < 4; rt++) {
                const int rbase = t0 + rt * 16 + (lane >> 4) * 4;
#pragma unroll
                for (int cb = 0; cb < 4; cb++) {
                    const int col = 64 * w + 16 * cb + (lane & 15);
                    const float bsum = b_ih1[col] + b_hh1[col];
#pragma unroll
                    for (int r = 0; r < 4; r++)
                        bufB[((size_t)b * T_SZ + rbase + r) * H_SZ + col] =
                            (half_t)(gac[rt][cb][r] + bsum);
                }
            }
            __syncthreads();   // drain all waves' bufB stores (vmcnt0 at barrier)
            if (tid == 0)
                __hip_atomic_store(&flags1[b * NCH + chunk], 1u, __ATOMIC_RELEASE,
                                   __HIP_MEMORY_SCOPE_AGENT);
        }
        return;
    }

    // ---------- recurrence (roles 0 and 2) ----------
    const bool L1 = (role == 2);
    const float* Whh = L1 ? Whh1 : Whh0;

    const int q  = l >> 3;    // row-group within wave
    const int sp = l & 7;     // K-slice within wave

    unsigned int wreg[208];   // [pair c][row r] = wreg[c*8+r], pairs 0..25
#pragma unroll
    for (int r = 0; r < 8; r++) {
        const float* wrow = Whh + (size_t)(64 * s + 8 * q + r) * H_SZ + 64 * sp;
#pragma unroll
        for (int c = 0; c < 26; c++)
            wreg[c * 8 + r] = pack_pair(wrow[2 * c], wrow[2 * c + 1]);
    }
#pragma unroll
    for (int p2 = 0; p2 < 4; p2++) {        // pairs 26..29 spill to LDS
#pragma unroll
        for (int rh = 0; rh < 2; rh++) {
            unsigned int qv[4];
#pragma unroll
            for (int rr = 0; rr < 4; rr++) {
                const int r = rh * 4 + rr;
                const float* wrow = Whh + (size_t)(64 * s + 8 * q + r) * H_SZ + 64 * sp;
                const int c = 26 + p2;
                qv[rr] = pack_pair(wrow[2 * c], wrow[2 * c + 1]);
            }
            uint4 v;
            v.x = qv[0]; v.y = qv[1]; v.z = qv[2]; v.w = qv[3];
            wlds[(p2 * 2 + rh) * 512 + tid] = v;
        }
    }
    // h0: thread owns element e = 64s + l -> slice s, offset l
    hpad[0][s * 72 + l] = (half_t)((L1 ? h0_1 : h0_0)[tid]);
    __syncthreads();

    unsigned short* xp16 = (unsigned short*)(L1 ? bufB : bufA);
    const size_t base = (size_t)b * T_SZ * H_SZ + tid;

    // per-lane read base: K-slice sp of each parity buffer (144 B stride,
    // 16B-aligned; the 8 broadcast addresses of each b128 cover disjoint
    // 4-bank groups -> conflict-free)
    const uint4* hp0 = (const uint4*)(&hpad[0][sp * 72]);
    const uint4* hp1 = (const uint4*)(&hpad[1][sp * 72]);
    half_t* hw0 = &hpad[0][s * 72 + l];
    half_t* hw1 = &hpad[1][s * 72 + l];

    // global W overflow base (pairs 30,31), layer-selected
    const uint4* wg = WovG + (size_t)(L1 ? 4 : 0) * 512 + tid;

    const bool sb0 = (sp & 1) != 0;
    const bool sb1 = (sp & 2) != 0;
    const bool sb2 = (sp & 4) != 0;

#pragma unroll 1
    for (int chunk = 0; chunk < NCH; chunk++) {
        const int t0 = chunk * CH;
        if (L1) {
            if (tid == 0) {
                while (__hip_atomic_load(&flags1[b * NCH + chunk], __ATOMIC_ACQUIRE,
                                         __HIP_MEMORY_SCOPE_AGENT) == 0u)
                    __builtin_amdgcn_s_sleep(2);
            }
            __syncthreads();
        }
        unsigned short xpw_next = xp16[base + (size_t)t0 * H_SZ];

#pragma unroll 1
        for (int tt = 0; tt < CH; tt++) {
            const int t = t0 + tt;
            const int par = tt & 1;
            const unsigned short xpw = xpw_next;
            if (tt + 1 < CH) xpw_next = xp16[base + (size_t)(t + 1) * H_SZ];

            float acc[8];
#pragma unroll
            for (int r = 0; r < 8; r++) acc[r] = 0.f;

            const uint4* hp = par ? hp1 : hp0;

            // ---- software-pipelined dot-product schedule ----
            uint4 hc  = hp[0];
            uint4 hA  = hp[6];
            uint4 hB  = hp[7];
            uint4 wv0 = wlds[0 * 512 + tid];
            uint4 wv1 = wlds[1 * 512 + tid];

#define REGBLK(CC, HV) { \
                const unsigned int hx0 = (HV).x, hx1 = (HV).y, hx2 = (HV).z, hx3 = (HV).w; \
                _Pragma("unroll") \
                for (int r = 0; r < 8; r++) acc[r] = fdot2(wreg[((CC) * 4 + 0) * 8 + r], hx0, acc[r]); \
                _Pragma("unroll") \
                for (int r = 0; r < 8; r++) acc[r] = fdot2(wreg[((CC) * 4 + 1) * 8 + r], hx1, acc[r]); \
                _Pragma("unroll") \
                for (int r = 0; r < 8; r++) acc[r] = fdot2(wreg[((CC) * 4 + 2) * 8 + r], hx2, acc[r]); \
                _Pragma("unroll") \
                for (int r = 0; r < 8; r++) acc[r] = fdot2(wreg[((CC) * 4 + 3) * 8 + r], hx3, acc[r]); }
#define CONSUME(H2) { \
                acc[0] = fdot2(wv0.x, (H2), acc[0]); acc[1] = fdot2(wv0.y, (H2), acc[1]); \
                acc[2] = fdot2(wv0.z, (H2), acc[2]); acc[3] = fdot2(wv0.w, (H2), acc[3]); \
                acc[4] = fdot2(wv1.x, (H2), acc[4]); acc[5] = fdot2(wv1.y, (H2), acc[5]); \
                acc[6] = fdot2(wv1.z, (H2), acc[6]); acc[7] = fdot2(wv1.w, (H2), acc[7]); }
#define CONSUMEG(GA, GB, H2) { \
                acc[0] = fdot2((GA).x, (H2), acc[0]); acc[1] = fdot2((GA).y, (H2), acc[1]); \
                acc[2] = fdot2((GA).z, (H2), acc[2]); acc[3] = fdot2((GA).w, (H2), acc[3]); \
                acc[4] = fdot2((GB).x, (H2), acc[4]); acc[5] = fdot2((GB).y, (H2), acc[5]); \
                acc[6] = fdot2((GB).z, (H2), acc[6]); acc[7] = fdot2((GB).w, (H2), acc[7]); }

            {
                uint4 hn;
                uint4 g0, g1, g2, g3;
                // stage 0: reg pairs 0..3, LDS pair 26
                hn = hp[1];  REGBLK(0, hc)  CONSUME(hA.z)
                wv0 = wlds[2 * 512 + tid];  wv1 = wlds[3 * 512 + tid];  hc = hn;
                // stage 1: reg pairs 4..7, LDS pair 27
                hn = hp[2];  REGBLK(1, hc)  CONSUME(hA.w)
                wv0 = wlds[4 * 512 + tid];  wv1 = wlds[5 * 512 + tid];  hc = hn;
                // stage 2: reg pairs 8..11, LDS pair 28
                hn = hp[3];  REGBLK(2, hc)  CONSUME(hB.x)
                wv0 = wlds[6 * 512 + tid];  wv1 = wlds[7 * 512 + tid];  hc = hn;
                g0 = wg[0 * 512];  g1 = wg[1 * 512];     // pair 30 (VMEM, L1-hit)
                // stage 3: reg pairs 12..15, LDS pair 29
                hn = hp[4];  REGBLK(3, hc)  CONSUME(hB.y)
                g2 = wg[2 * 512];  g3 = wg[3 * 512];     // pair 31
                hc = hn;
                // stage 4: reg pairs 16..19, global pair 30
                hn = hp[5];  REGBLK(4, hc)  CONSUMEG(g0, g1, hB.z)
                hc = hn;
                // stage 5: reg pairs 20..23, global pair 31
                REGBLK(5, hc)  CONSUMEG(g2, g3, hB.w)
                // tail: reg pairs 24,25
                {
                    const unsigned int hx0 = hA.x, hx1 = hA.y;
#pragma unroll
                    for (int r = 0; r < 8; r++) acc[r] = fdot2(wreg[24 * 8 + r], hx0, acc[r]);
#pragma unroll
                    for (int r = 0; r < 8; r++) acc[r] = fdot2(wreg[25 * 8 + r], hx1, acc[r]);
                }
            }
#undef REGBLK
#undef CONSUME
#undef CONSUMEG

            // in-wave reduction over the 8 K-slice lanes (VALU pipe only)
#pragma unroll
            for (int r = 0; r < 8; r++) {
                float a = acc[r];
                a = dpp_add<0x0B1>(a);   // + lane^1
                a = dpp_add<0x04E>(a);   // + lane^2
                a = dpp_add<0x141>(a);   // + lane^7 (other quad's quad-sum)
                acc[r] = a;
            }
            // lane keeps row 8q + sp  ->  select acc[sp]
            float t0s = sb0 ? acc[1] : acc[0];
            float t1s = sb0 ? acc[3] : acc[2];
            float t2s = sb0 ? acc[5] : acc[4];
            float t3s = sb0 ? acc[7] : acc[6];
            float u0s = sb1 ? t1s : t0s;
            float u1s = sb1 ? t3s : t2s;
            float rsum = sb2 ? u1s : u0s;

            float y;
            {
                half_t xv = __builtin_bit_cast(half_t, xpw);
                y = (float)xv + rsum;
            }
            float e   = __expf(2.0f * y);
            float hn2 = 1.0f - 2.0f * fast_rcp(e + 1.0f);

            *(par ? hw0 : hw1) = (half_t)hn2;   // next step's h (parity flip)
            if (!L1)
                xp16[base + (size_t)t * H_SZ] = __builtin_bit_cast(unsigned short, (half_t)hn2);
            else if (t == T_SZ - 1)
                hT[(size_t)b * H_SZ + tid] = hn2;

            step_barrier();    // lgkmcnt(0) + s_barrier: NO vmcnt drain
        }
        if (!L1) {
            __syncthreads();   // real barrier: vmcnt0 drains this chunk's res stores
            if (tid == 0)
                __hip_atomic_store(&flags0[b * NCH + chunk], 1u, __ATOMIC_RELEASE,
                                   __HIP_MEMORY_SCOPE_AGENT);
        }
    }
}

// ---------------- head ----------------
__global__ __launch_bounds__(128) void head_fc(const float* __restrict__ hT,
                                               const float* __restrict__ Wfc,
                                               const float* __restrict__ bfc,
                                               float* __restrict__ out)
{
    __shared__ float hs[H_SZ];
    const int b = blockIdx.x, o = threadIdx.x;
    for (int i = o; i < H_SZ; i += 128) hs[i] = hT[(size_t)b * H_SZ + i];
    __syncthreads();
    const float4* w4 = (const float4*)(Wfc + (size_t)o * H_SZ);
    const float4* h4 = (const float4*)hs;
    float acc = 0.f;
#pragma unroll 4
    for (int k = 0; k < H_SZ / 4; k++) {
        float4 w = w4[k], h = h4[k];
        acc += w.x * h.x + w.y * h.y + w.z * h.z + w.w * h.w;
    }
    out[(size_t)b * O_SZ + o] = acc + bfc[o];
}

// ---------------- launch ----------------

extern "C" void kernel_launch(void* const* d_in, const int* in_sizes, int n_in,
                              void* d_out, int out_size, void* d_ws, size_t ws_size,
                              hipStream_t stream) {
    const float* x     = (const float*)d_in[0];
    const float* W_ih0 = (const float*)d_in[1];
    const float* W_hh0 = (const float*)d_in[2];
    const float* b_ih0 = (const float*)d_in[3];
    const float* b_hh0 = (const float*)d_in[4];
    const float* h0_0  = (const float*)d_in[5];
    const float* W_ih1 = (const float*)d_in[6];
    const float* W_hh1 = (const float*)d_in[7];
    const float* b_ih1 = (const float*)d_in[8];
    const float* b_hh1 = (const float*)d_in[9];
    const float* h0_1  = (const float*)d_in[10];
    const float* W_fc  = (const float*)d_in[11];
    const float* b_fc  = (const float*)d_in[12];

    char* ws = (char*)d_ws;
    size_t off = 0;
    const size_t bufElems = (size_t)B_SZ * T_SZ * H_SZ;          // 67,108,864
    half_t* bufA  = (half_t*)(ws + off); off += bufElems * 2;    // xp0 -> res (in place)
    half_t* bufB  = (half_t*)(ws + off); off += bufElems * 2;    // xp1 (per-chunk producer)
    half_t* Wih0h = (half_t*)(ws + off); off += (size_t)H_SZ * F_SZ * 2;
    half_t* Wih1h = (half_t*)(ws + off); off += (size_t)H_SZ * H_SZ * 2;
    float*  hTbuf = (float*)(ws + off);  off += (size_t)B_SZ * H_SZ * 4;
    const int FLAG_N = B_SZ * NCH;
    unsigned int* flags0 = (unsigned int*)(ws + off); off += (size_t)FLAG_N * 4;
    unsigned int* flags1 = (unsigned int*)(ws + off); off += (size_t)FLAG_N * 4;
    uint4* WovG = (uint4*)(ws + off); off += (size_t)2 * 4 * 512 * 16;  // 64 KB

    const int M = B_SZ * T_SZ;   // 131072

    zero_flags<<<(2 * FLAG_N + 255) / 256, 256, 0, stream>>>(flags0, 2 * FLAG_N);
    cvt_f32_f16<<<(H_SZ * F_SZ + 255) / 256, 256, 0, stream>>>(W_ih0, Wih0h, H_SZ * F_SZ);
    cvt_f32_f16<<<(H_SZ * H_SZ + 255) / 256, 256, 0, stream>>>(W_ih1, Wih1h, H_SZ * H_SZ);
    pack_wov<<<4, 256, 0, stream>>>(W_hh0, W_hh1, WovG);

    // xp0 = x @ W_ih0^T + b_ih0 + b_hh0
    gemm_xp<true, F_SZ><<<(M / 64) * 8, 256, 0, stream>>>(x, Wih0h, b_ih0, b_hh0, bufA);

    // pipelined: layer-0 rec + xp1 producer + layer-1 rec, all concurrent
    rnn_mega<<<192, 512, 0, stream>>>(bufA, bufB, W_hh0, W_hh1, Wih1h,
                                      h0_0, h0_1, b_ih1, b_hh1, WovG,
                                      hTbuf, flags0, flags1);

    head_fc<<<B_SZ, 128, 0, stream>>>(hTbuf, W_fc, b_fc, (float*)d_out);
}

// Round 6
// 3905.535 us; speedup vs baseline: 1.6665x; 1.6665x over previous
//
#include <hip/hip_runtime.h>

typedef _Float16 half_t;
typedef _Float16 f16x2 __attribute__((ext_vector_type(2)));
typedef _Float16 f16x8 __attribute__((ext_vector_type(8)));
typedef float f32x4 __attribute__((ext_vector_type(4)));

#define B_SZ 64
#define T_SZ 2048
#define F_SZ 256
#define H_SZ 512
#define O_SZ 128
#define NCH 32      // chunks
#define CH 64       // timesteps per chunk

#if defined(__has_builtin)
#if __has_builtin(__builtin_amdgcn_rcpf)
#define HAS_RCPF 1
#endif
#endif
#ifndef HAS_RCPF
#define HAS_RCPF 0
#endif

static __device__ __forceinline__ float fast_rcp(float x) {
#if HAS_RCPF
    return __builtin_amdgcn_rcpf(x);
#else
    return 1.0f / x;
#endif
}

// Per-step barrier: LDS-only drain. __syncthreads() would add a vmcnt(0)
// drain of the in-flight xp prefetch / res store every step.
static __device__ __forceinline__ void step_barrier() {
    __builtin_amdgcn_sched_barrier(0);
    asm volatile("s_waitcnt lgkmcnt(0)" ::: "memory");
    __builtin_amdgcn_s_barrier();
    __builtin_amdgcn_sched_barrier(0);
}

// ---------------- prep ----------------

__global__ void cvt_f32_f16(const float* __restrict__ src, half_t* __restrict__ dst, int n) {
    int i = blockIdx.x * 256 + threadIdx.x;
    if (i < n) dst[i] = (half_t)src[i];
}

__global__ void zero_flags(unsigned int* __restrict__ p, int n) {
    int i = blockIdx.x * 256 + threadIdx.x;
    if (i < n) p[i] = 0u;
}

// ---------------- xp0 GEMM (MFMA f16), layer-0 input projection ----------------
template<bool A_F32, int K>
__global__ __launch_bounds__(256) void gemm_xp(const void* __restrict__ Aptr,
                                               const half_t* __restrict__ Bw,
                                               const float* __restrict__ bias1,
                                               const float* __restrict__ bias2,
                                               half_t* __restrict__ Cout)
{
    const int nt   = blockIdx.x & 7;
    const int mt   = blockIdx.x >> 3;
    const int wave = threadIdx.x >> 6;
    const int lane = threadIdx.x & 63;
    const int mrow = mt * 64 + wave * 16 + (lane & 15);
    const int koff = (lane >> 4) * 8;

    f32x4 acc[4];
#pragma unroll
    for (int i = 0; i < 4; i++) acc[i] = (f32x4){0.f, 0.f, 0.f, 0.f};

#pragma unroll 2
    for (int k0 = 0; k0 < K; k0 += 32) {
        f16x8 a;
        if (A_F32) {
            const float* ap = (const float*)Aptr + (size_t)mrow * K + (k0 + koff);
            float4 v0 = ((const float4*)ap)[0];
            float4 v1 = ((const float4*)ap)[1];
            a[0] = (half_t)v0.x; a[1] = (half_t)v0.y; a[2] = (half_t)v0.z; a[3] = (half_t)v0.w;
            a[4] = (half_t)v1.x; a[5] = (half_t)v1.y; a[6] = (half_t)v1.z; a[7] = (half_t)v1.w;
        } else {
            const half_t* ap = (const half_t*)Aptr + (size_t)mrow * K + (k0 + koff);
            a = *(const f16x8*)ap;
        }
#pragma unroll
        for (int cb = 0; cb < 4; cb++) {
            const int col = nt * 64 + cb * 16 + (lane & 15);
            f16x8 bfrag = *(const f16x8*)(Bw + (size_t)col * K + (k0 + koff));
            acc[cb] = __builtin_amdgcn_mfma_f32_16x16x32_f16(a, bfrag, acc[cb], 0, 0, 0);
        }
    }
    const int rbase = mt * 64 + wave * 16 + (lane >> 4) * 4;
#pragma unroll
    for (int cb = 0; cb < 4; cb++) {
        const int col = nt * 64 + cb * 16 + (lane & 15);
        const float bsum = bias1[col] + bias2[col];
#pragma unroll
        for (int r = 0; r < 4; r++) {
            Cout[(size_t)(rbase + r) * H_SZ + col] = (half_t)(acc[cb][r] + bsum);
        }
    }
}

// ---------------- mega-kernel: pipelined 2-layer RNN ----------------
// 192 blocks x 512 threads, role = blockIdx.x % 3, b = blockIdx.x / 3:
//  role 0: layer-0 recurrence on bufA (xp0 -> res in place); releases
//          flags0[b][chunk] after each 64-step chunk (agent scope).
//  role 1: xp1 producer: polls flags0, MFMA-GEMMs res chunk @ W_ih1^T + bias
//          into bufB, releases flags1[b][chunk].
//  role 2: layer-1 recurrence on bufB; polls flags1; writes hT at t=T-1.
//
// Rec step = MFMA matvec (replaces 256 fdot2 + DPP reduce per thread):
//  wave s owns rows 64s..64s+63 as 4 N-tiles of mfma_f32_16x16x32_f16.
//  A-operand = h BROADCAST across all 16 M-rows (A[m][k]=h[k] for all m, so
//  all D rows are identical -> no masking; lane's A-frag read is one
//  ds_read_b128 at addr depending only on lane>>4: 4 disjoint-bank broadcast
//  addresses, conflict-free). B-frags = W_hh rows in the verified gemm_xp
//  layout (n=lane&15, k=(lane>>4)*8+j): K-tiles 0..12 resident in VGPR+AGPR
//  (208 regs), K-tiles 13..15 streamed from LDS (12 ds_read_b128/thread).
//  D col=lane&15, rows identical -> lane l's output element = 64s + l = tid
//  (xp/res/hT indexing unchanged from the fdot2 version). h exchanged via a
//  parity double-buffered linear LDS f16 buffer (b16 write = 2-way free;
//  reads conflict-free as above). One lgkm-only barrier per step.
__global__ __launch_bounds__(512, 2)
void rnn_mega(half_t* bufA, half_t* bufB,
              const float* __restrict__ Whh0, const float* __restrict__ Whh1,
              const half_t* __restrict__ Wih1h,
              const float* __restrict__ h0_0, const float* __restrict__ h0_1,
              const float* __restrict__ b_ih1, const float* __restrict__ b_hh1,
              float* hT,
              unsigned int* flags0, unsigned int* flags1)
{
    __shared__ __align__(16) uint4  wlds[12 * 512];   // 96 KB (B-frags, K-tiles 13..15)
    __shared__ __align__(16) half_t hbuf[2][H_SZ];    // 2 KB (h, parity)

    const int role = blockIdx.x % 3;
    const int b    = blockIdx.x / 3;
    const int tid  = threadIdx.x;
    const int l    = tid & 63;
    const int s    = tid >> 6;

    if (role == 1) {
        // ---------- xp1 chunk-GEMM producer ----------
        const int w = s, lane = l;
        const int koff = (lane >> 4) * 8;
        for (int chunk = 0; chunk < NCH; chunk++) {
            if (tid == 0) {
                while (__hip_atomic_load(&flags0[b * NCH + chunk], __ATOMIC_ACQUIRE,
                                         __HIP_MEMORY_SCOPE_AGENT) == 0u)
                    __builtin_amdgcn_s_sleep(2);
            }
            __syncthreads();   // all threads gated; acquire-inv done by wave 0
            const int t0 = chunk * CH;

            f32x4 gac[4][4];
#pragma unroll
            for (int rt = 0; rt < 4; rt++)
#pragma unroll
                for (int cb = 0; cb < 4; cb++) gac[rt][cb] = (f32x4){0.f, 0.f, 0.f, 0.f};

#pragma unroll 1
            for (int k0 = 0; k0 < H_SZ; k0 += 32) {
                f16x8 bf[4];
#pragma unroll
                for (int cb = 0; cb < 4; cb++)
                    bf[cb] = *(const f16x8*)(Wih1h +
                              (size_t)(64 * w + 16 * cb + (lane & 15)) * H_SZ + k0 + koff);
#pragma unroll
                for (int rt = 0; rt < 4; rt++) {
                    const f16x8 a = *(const f16x8*)((const half_t*)bufA +
                              ((size_t)b * T_SZ + t0 + rt * 16 + (lane & 15)) * H_SZ + k0 + koff);
#pragma unroll
                    for (int cb = 0; cb < 4; cb++)
                        gac[rt][cb] = __builtin_amdgcn_mfma_f32_16x16x32_f16(a, bf[cb], gac[rt][cb], 0, 0, 0);
                }
            }
#pragma unroll
            for (int rt = 0; rt < 4; rt++) {
                const int rbase = t0 + rt * 16 + (lane >> 4) * 4;
#pragma unroll
                for (int cb = 0; cb < 4; cb++) {
                    const int col = 64 * w + 16 * cb + (lane & 15);
                    const float bsum = b_ih1[col] + b_hh1[col];
#pragma unroll
                    for (int r = 0; r < 4; r++)
                        bufB[((size_t)b * T_SZ + rbase + r) * H_SZ + col] =
                            (half_t)(gac[rt][cb][r] + bsum);
                }
            }
            __syncthreads();   // drain all waves' bufB stores (vmcnt0 at barrier)
            if (tid == 0)
                __hip_atomic_store(&flags1[b * NCH + chunk], 1u, __ATOMIC_RELEASE,
                                   __HIP_MEMORY_SCOPE_AGENT);
        }
        return;
    }

    // ---------- recurrence (roles 0 and 2), MFMA matvec ----------
    const bool L1 = (role == 2);
    const float* Whh = L1 ? Whh1 : Whh0;

    const int n15 = l & 15;     // output col within N-tile
    const int kg  = l >> 4;     // k-group (0..3) within K-tile

    // B-frags, K-tiles 0..12 resident (13 x 4 x 4 regs = 208)
    f16x8 breg[13][4];
#pragma unroll
    for (int kt = 0; kt < 13; kt++) {
#pragma unroll
        for (int n = 0; n < 4; n++) {
            const float* wr = Whh + (size_t)(64 * s + 16 * n + n15) * H_SZ + 32 * kt + 8 * kg;
            f16x8 f;
#pragma unroll
            for (int j = 0; j < 8; j++) f[j] = (half_t)wr[j];
            breg[kt][n] = f;
        }
    }
    // B-frags, K-tiles 13..15 -> LDS
#pragma unroll
    for (int kt2 = 0; kt2 < 3; kt2++) {
#pragma unroll
        for (int n = 0; n < 4; n++) {
            const float* wr = Whh + (size_t)(64 * s + 16 * n + n15) * H_SZ + 32 * (13 + kt2) + 8 * kg;
            f16x8 f;
#pragma unroll
            for (int j = 0; j < 8; j++) f[j] = (half_t)wr[j];
            wlds[(kt2 * 4 + n) * 512 + tid] = __builtin_bit_cast(uint4, f);
        }
    }
    hbuf[0][tid] = (half_t)((L1 ? h0_1 : h0_0)[tid]);
    __syncthreads();

    unsigned short* xp16 = (unsigned short*)(L1 ? bufB : bufA);
    const size_t base = (size_t)b * T_SZ * H_SZ + tid;   // element e = tid

#pragma unroll 1
    for (int chunk = 0; chunk < NCH; chunk++) {
        const int t0 = chunk * CH;
        if (L1) {
            if (tid == 0) {
                while (__hip_atomic_load(&flags1[b * NCH + chunk], __ATOMIC_ACQUIRE,
                                         __HIP_MEMORY_SCOPE_AGENT) == 0u)
                    __builtin_amdgcn_s_sleep(2);
            }
            __syncthreads();
        }
        unsigned short xpw_next = xp16[base + (size_t)t0 * H_SZ];

#pragma unroll 1
        for (int tt = 0; tt < CH; tt++) {
            const int t = t0 + tt;
            const int par = tt & 1;
            const unsigned short xpw = xpw_next;
            if (tt + 1 < CH) xpw_next = xp16[base + (size_t)(t + 1) * H_SZ];

            const half_t* hc_ = hbuf[par];

            f32x4 acc[4];
#pragma unroll
            for (int n = 0; n < 4; n++) acc[n] = (f32x4){0.f, 0.f, 0.f, 0.f};

            // register-resident K-tiles: A-frag = broadcast h slice
#pragma unroll
            for (int kt = 0; kt < 13; kt++) {
                const f16x8 a = *(const f16x8*)(hc_ + 32 * kt + 8 * kg);
#pragma unroll
                for (int n = 0; n < 4; n++)
                    acc[n] = __builtin_amdgcn_mfma_f32_16x16x32_f16(a, breg[kt][n], acc[n], 0, 0, 0);
            }
            // LDS-streamed K-tiles 13..15
#pragma unroll
            for (int kt2 = 0; kt2 < 3; kt2++) {
                const f16x8 a = *(const f16x8*)(hc_ + 32 * (13 + kt2) + 8 * kg);
#pragma unroll
                for (int n = 0; n < 4; n++) {
                    const f16x8 bf = __builtin_bit_cast(f16x8, wlds[(kt2 * 4 + n) * 512 + tid]);
                    acc[n] = __builtin_amdgcn_mfma_f32_16x16x32_f16(a, bf, acc[n], 0, 0, 0);
                }
            }

            // lane's element e = 64s + l: tile n = kg, col = n15; D rows are
            // identical (broadcast A) -> take reg 0, select tile via 3 cndmask
            float va   = (kg & 1) ? acc[1][0] : acc[0][0];
            float vb   = (kg & 1) ? acc[3][0] : acc[2][0];
            float rsum = (kg & 2) ? vb : va;

            half_t xv = __builtin_bit_cast(half_t, xpw);
            float y   = (float)xv + rsum;
            float e2  = __expf(2.0f * y);
            float hn2 = 1.0f - 2.0f * fast_rcp(e2 + 1.0f);

            hbuf[par ^ 1][tid] = (half_t)hn2;   // next step's h (parity flip)
            if (!L1)
                xp16[base + (size_t)t * H_SZ] = __builtin_bit_cast(unsigned short, (half_t)hn2);
            else if (t == T_SZ - 1)
                hT[(size_t)b * H_SZ + tid] = hn2;

            step_barrier();    // lgkmcnt(0) + s_barrier: NO vmcnt drain
        }
        if (!L1) {
            __syncthreads();   // real barrier: vmcnt0 drains this chunk's res stores
            if (tid == 0)
                __hip_atomic_store(&flags0[b * NCH + chunk], 1u, __ATOMIC_RELEASE,
                                   __HIP_MEMORY_SCOPE_AGENT);
        }
    }
}

// ---------------- head ----------------
__global__ __launch_bounds__(128) void head_fc(const float* __restrict__ hT,
                                               const float* __restrict__ Wfc,
                                               const float* __restrict__ bfc,
                                               float* __restrict__ out)
{
    __shared__ float hs[H_SZ];
    const int b = blockIdx.x, o = threadIdx.x;
    for (int i = o; i < H_SZ; i += 128) hs[i] = hT[(size_t)b * H_SZ + i];
    __syncthreads();
    const float4* w4 = (const float4*)(Wfc + (size_t)o * H_SZ);
    const float4* h4 = (const float4*)hs;
    float acc = 0.f;
#pragma unroll 4
    for (int k = 0; k < H_SZ / 4; k++) {
        float4 w = w4[k], h = h4[k];
        acc += w.x * h.x + w.y * h.y + w.z * h.z + w.w * h.w;
    }
    out[(size_t)b * O_SZ + o] = acc + bfc[o];
}

// ---------------- launch ----------------

extern "C" void kernel_launch(void* const* d_in, const int* in_sizes, int n_in,
                              void* d_out, int out_size, void* d_ws, size_t ws_size,
                              hipStream_t stream) {
    const float* x     = (const float*)d_in[0];
    const float* W_ih0 = (const float*)d_in[1];
    const float* W_hh0 = (const float*)d_in[2];
    const float* b_ih0 = (const float*)d_in[3];
    const float* b_hh0 = (const float*)d_in[4];
    const float* h0_0  = (const float*)d_in[5];
    const float* W_ih1 = (const float*)d_in[6];
    const float* W_hh1 = (const float*)d_in[7];
    const float* b_ih1 = (const float*)d_in[8];
    const float* b_hh1 = (const float*)d_in[9];
    const float* h0_1  = (const float*)d_in[10];
    const float* W_fc  = (const float*)d_in[11];
    const float* b_fc  = (const float*)d_in[12];

    char* ws = (char*)d_ws;
    size_t off = 0;
    const size_t bufElems = (size_t)B_SZ * T_SZ * H_SZ;          // 67,108,864
    half_t* bufA  = (half_t*)(ws + off); off += bufElems * 2;    // xp0 -> res (in place)
    half_t* bufB  = (half_t*)(ws + off); off += bufElems * 2;    // xp1 (per-chunk producer)
    half_t* Wih0h = (half_t*)(ws + off); off += (size_t)H_SZ * F_SZ * 2;
    half_t* Wih1h = (half_t*)(ws + off); off += (size_t)H_SZ * H_SZ * 2;
    float*  hTbuf = (float*)(ws + off);  off += (size_t)B_SZ * H_SZ * 4;
    const int FLAG_N = B_SZ * NCH;
    unsigned int* flags0 = (unsigned int*)(ws + off); off += (size_t)FLAG_N * 4;
    unsigned int* flags1 = (unsigned int*)(ws + off); off += (size_t)FLAG_N * 4;

    const int M = B_SZ * T_SZ;   // 131072

    zero_flags<<<(2 * FLAG_N + 255) / 256, 256, 0, stream>>>(flags0, 2 * FLAG_N);
    cvt_f32_f16<<<(H_SZ * F_SZ + 255) / 256, 256, 0, stream>>>(W_ih0, Wih0h, H_SZ * F_SZ);
    cvt_f32_f16<<<(H_SZ * H_SZ + 255) / 256, 256, 0, stream>>>(W_ih1, Wih1h, H_SZ * H_SZ);

    // xp0 = x @ W_ih0^T + b_ih0 + b_hh0
    gemm_xp<true, F_SZ><<<(M / 64) * 8, 256, 0, stream>>>(x, Wih0h, b_ih0, b_hh0, bufA);

    // pipelined: layer-0 rec + xp1 producer + layer-1 rec, all concurrent
    rnn_mega<<<192, 512, 0, stream>>>(bufA, bufB, W_hh0, W_hh1, Wih1h,
                                      h0_0, h0_1, b_ih1, b_hh1,
                                      hTbuf, flags0, flags1);

    head_fc<<<B_SZ, 128, 0, stream>>>(hTbuf, W_fc, b_fc, (float*)d_out);
}